// Round 4
// baseline (493.923 us; speedup 1.0000x reference)
//
#include <hip/hip_runtime.h>
#include <math.h>

typedef unsigned short ushort_t;

#define N_ROWS 32768
#define DIM 256
#define KCENT 2048

// ---------------- fp32 fallback path constants (round-1 kernel) -------------
#define NSPLIT 4
#define CPG (KCENT / NSPLIT)
#define BM 64
#define BN 64
#define BKK 32
#define LSTR 36

#define WS_SUMSQ  0
#define WS_CSQ    32768
#define WS_COUNTS 34816
#define WS_IDX    36864
#define WS_PVAL   69632
#define WS_PIDX   200704

// ---------------- output layout (float offsets) -----------------------------
#define OUT_Q    0
#define OUT_LOSS 8388608
#define OUT_IDX  16777216
#define OUT_CB   16809984
#define OUT_CNT  17334272

// ---------------- MFMA path workspace (byte offsets) ------------------------
// 8 partial groups per row (4 block-groups x 2 wn-halves)
#define WB_A2     0UL            // 32768 x 512 f16 = [x_hi | x_lo]  (32 MB)
#define WB_B2     33554432UL     // 2048 x 512 f16 = [c_hi | c_lo]   (2 MB)
#define WB_PV1    35651584UL     // 8 x 32768 f32  (1 MB)
#define WB_PI1    36700160UL     // 8 x 32768 i32  (1 MB)
#define WB_PV2    37748736UL     // 8 x 32768 f32  (1 MB)
#define WB_SUMSQ  38797312UL     // 32768 f32 (exact ||x||^2)
#define WB_XLO    38928384UL     // 32768 f32 (||x_lo||)
#define WB_XR     39059456UL     // 32768 f32 (||r_x||)
#define WB_CSQ    39190528UL     // 2048 f32 (exact ||c||^2)
#define WB_COUNTS 39198720UL     // 2048 f32
#define WB_IDXBUF 39206912UL     // 32768 i32
#define WB_RLIST  39337984UL     // 32768 i32
#define WB_MISC   39469056UL     // rcnt(i32) @ +0, maxes(u32[3]) @ +8
#define WS_NEED   39469120UL

// ---------------- types & helpers -------------------------------------------
typedef _Float16 half4 __attribute__((ext_vector_type(4)));
typedef _Float16 half8 __attribute__((ext_vector_type(8)));
typedef float f32x4 __attribute__((ext_vector_type(4)));

#define ASYNC_COPY16(gptr, lptr)                                               \
  __builtin_amdgcn_global_load_lds(                                            \
      (const __attribute__((address_space(1))) void*)(gptr),                   \
      (__attribute__((address_space(3))) void*)(lptr), 16, 0, 0)

// ============================================================================
//                               MFMA PATH (fp16 3-term split)
// ============================================================================

__global__ __launch_bounds__(256) void vq_init(float* counts, int* rcnt, unsigned* maxes) {
  int tid = threadIdx.x;
  for (int i = tid; i < KCENT; i += 256) counts[i] = 0.0f;
  if (tid == 0) { *rcnt = 0; maxes[0] = 0u; maxes[1] = 0u; maxes[2] = 0u; }
}

// split X into f16 hi/lo + per-row norms; one wave per row
__global__ __launch_bounds__(256) void vq_conv_x(
    const float* __restrict__ X, _Float16* __restrict__ A2,
    float* __restrict__ sumsq, float* __restrict__ xlo_n, float* __restrict__ xr_n)
{
  int row = blockIdx.x * 4 + (threadIdx.x >> 6);
  int lane = threadIdx.x & 63;
  float4 v = *(const float4*)(X + (size_t)row * DIM + lane * 4);
  float xv[4] = {v.x, v.y, v.z, v.w};
  half4 hv, lv;
  float s2 = 0.f, l2 = 0.f, r2 = 0.f;
#pragma unroll
  for (int e = 0; e < 4; ++e) {
    float x = xv[e];
    _Float16 h = (_Float16)x;          // RNE
    float hf = (float)h;
    float lrem = x - hf;
    _Float16 l = (_Float16)lrem;
    float lf = (float)l;
    float r = lrem - lf;
    hv[e] = h; lv[e] = l;
    s2 += x * x; l2 += lf * lf; r2 += r * r;
  }
  *(half4*)(A2 + (size_t)row * 512 + lane * 4) = hv;
  *(half4*)(A2 + (size_t)row * 512 + 256 + lane * 4) = lv;
#pragma unroll
  for (int off = 32; off > 0; off >>= 1) {
    s2 += __shfl_down(s2, off);
    l2 += __shfl_down(l2, off);
    r2 += __shfl_down(r2, off);
  }
  if (lane == 0) { sumsq[row] = s2; xlo_n[row] = sqrtf(l2); xr_n[row] = sqrtf(r2); }
}

// split C into f16 [hi|lo] + per-cent norms + global maxes; one wave per centroid
__global__ __launch_bounds__(256) void vq_conv_c(
    const float* __restrict__ C, _Float16* __restrict__ B2,
    float* __restrict__ csq, unsigned* __restrict__ maxes)
{
  int c = blockIdx.x * 4 + (threadIdx.x >> 6);
  int lane = threadIdx.x & 63;
  float4 v = *(const float4*)(C + (size_t)c * DIM + lane * 4);
  float xv[4] = {v.x, v.y, v.z, v.w};
  half4 hv, lv;
  float s2 = 0.f, l2 = 0.f, r2 = 0.f;
#pragma unroll
  for (int e = 0; e < 4; ++e) {
    float x = xv[e];
    _Float16 h = (_Float16)x;
    float hf = (float)h;
    float lrem = x - hf;
    _Float16 l = (_Float16)lrem;
    float lf = (float)l;
    float r = lrem - lf;
    hv[e] = h; lv[e] = l;
    s2 += x * x; l2 += lf * lf; r2 += r * r;
  }
  *(half4*)(B2 + (size_t)c * 512 + lane * 4) = hv;
  *(half4*)(B2 + (size_t)c * 512 + 256 + lane * 4) = lv;
#pragma unroll
  for (int off = 32; off > 0; off >>= 1) {
    s2 += __shfl_down(s2, off);
    l2 += __shfl_down(l2, off);
    r2 += __shfl_down(r2, off);
  }
  if (lane == 0) {
    csq[c] = s2;
    atomicMax(&maxes[0], __float_as_uint(sqrtf(l2)));   // max ||c_lo||
    atomicMax(&maxes[1], __float_as_uint(sqrtf(s2)));   // max ||c||
    atomicMax(&maxes[2], __float_as_uint(sqrtf(r2)));   // max ||r_c||
  }
}

// MFMA GEMM (virtual K=768: hi*hi + lo*hi + hi*lo) + fused argmin(+2nd-min).
// Block: 128 rows x 512 cents (4 internal 128-col tiles), grid (4, 256).
// Partial-group slot = g*2 + wn  (waves wn=0/1 cover DIFFERENT cent halves of
// the SAME rows -> they must write different slots; round-3 bug was writing g).
#define GBM 128
#define GBN 128
#define GBK 32
__global__ __launch_bounds__(256) void vq_mfma(
    const _Float16* __restrict__ A2, const _Float16* __restrict__ B2,
    const float* __restrict__ csq,
    float* __restrict__ pv1, int* __restrict__ pi1, float* __restrict__ pv2)
{
  __shared__ __align__(16) _Float16 sA[GBM * GBK];
  __shared__ __align__(16) _Float16 sB[GBN * GBK];

  const int tid = threadIdx.x;
  const int wave = tid >> 6, lane = tid & 63;
  const int lc = lane & 15, quad = lane >> 4;
  const int wm = wave >> 1, wn = wave & 1;
  const int row0 = blockIdx.y * GBM;
  const int g = blockIdx.x;           // cent group: cents [g*512, g*512+512)

  // running per-lane argmin state over this lane's cent slice (16 cents/row)
  float m1[4][4], m2[4][4];
  int i1v[4][4];
#pragma unroll
  for (int i = 0; i < 4; ++i)
#pragma unroll
    for (int r = 0; r < 4; ++r) { m1[i][r] = 3.4e38f; m2[i][r] = 3.4e38f; i1v[i][r] = 0; }

  // staging geometry
  const int st_row = wave * 32 + (lane >> 2);
  const int st_ko = (lane & 3) * 8;
  const _Float16* gA = A2 + (size_t)(row0 + st_row) * 512 + st_ko;

  for (int ct = 0; ct < 4; ++ct) {
    const int cb0 = g * 512 + ct * 128;
    const _Float16* gB = B2 + (size_t)(cb0 + st_row) * 512 + st_ko;
    float cs[4];
#pragma unroll
    for (int j = 0; j < 4; ++j) cs[j] = csq[cb0 + wn * 64 + j * 16 + lc];

    f32x4 acc[4][4] = {};

    for (int kt = 0; kt < 24; ++kt) {
      const int a_k0 = (kt < 16 ? kt : kt - 16) * 32;   // A: [hi | lo | hi]
      const int b_k0 = (kt < 8 ? kt : kt - 8) * 32;     // B: [hi | hi | lo]
      __syncthreads();
#pragma unroll
      for (int j = 0; j < 2; ++j) {
        ASYNC_COPY16(gA + (size_t)(j * 16) * 512 + a_k0, &sA[(wave * 32 + j * 16) * GBK]);
        ASYNC_COPY16(gB + (size_t)(j * 16) * 512 + b_k0, &sB[(wave * 32 + j * 16) * GBK]);
      }
      __syncthreads();
      half8 fa[4], fb[4];
#pragma unroll
      for (int i = 0; i < 4; ++i)
        fa[i] = *(const half8*)&sA[(wm * 64 + i * 16 + lc) * GBK + quad * 8];
#pragma unroll
      for (int j = 0; j < 4; ++j)
        fb[j] = *(const half8*)&sB[(wn * 64 + j * 16 + lc) * GBK + quad * 8];
#pragma unroll
      for (int i = 0; i < 4; ++i)
#pragma unroll
        for (int j = 0; j < 4; ++j)
          acc[i][j] = __builtin_amdgcn_mfma_f32_16x16x32_f16(fa[i], fb[j], acc[i][j], 0, 0, 0);
    }

    // fold this col-tile into running (m1, i1, m2); d drops ||x||^2 (row-const)
#pragma unroll
    for (int i = 0; i < 4; ++i) {
#pragma unroll
      for (int j = 0; j < 4; ++j) {
        const int cent = cb0 + wn * 64 + j * 16 + lc;
#pragma unroll
        for (int r = 0; r < 4; ++r) {
          float d = fmaf(-2.0f, acc[i][j][r], cs[j]);
          bool cnd = d < m1[i][r];
          i1v[i][r] = cnd ? cent : i1v[i][r];
          m2[i][r] = fminf(m2[i][r], fmaxf(d, m1[i][r]));
          m1[i][r] = fminf(d, m1[i][r]);
        }
      }
    }
  }

  // cross-lane reduce over the 16 lc lanes (branchless); ties -> gap 0 -> rescued
#pragma unroll
  for (int i = 0; i < 4; ++i) {
#pragma unroll
    for (int r = 0; r < 4; ++r) {
      float a1 = m1[i][r], a2 = m2[i][r];
      int ai = i1v[i][r];
#pragma unroll
      for (int off = 1; off < 16; off <<= 1) {
        float o1 = __shfl_xor(a1, off);
        int oi = __shfl_xor(ai, off);
        float o2 = __shfl_xor(a2, off);
        float big = fmaxf(a1, o1);
        bool cnd = o1 < a1;
        a1 = fminf(a1, o1);
        ai = cnd ? oi : ai;
        a2 = fminf(fminf(a2, o2), big);
      }
      if (lc == 0) {
        const int row = row0 + wm * 64 + i * 16 + quad * 4 + r;
        const int slot = g * 2 + wn;     // <- distinct slot per wn half
        pv1[slot * N_ROWS + row] = a1;
        pi1[slot * N_ROWS + row] = ai;
        pv2[slot * N_ROWS + row] = a2;
      }
    }
  }
}

// merge 8 partial groups/row; certify via window; flag uncertified rows
__global__ __launch_bounds__(256) void vq_flagreduce(
    const float* __restrict__ pv1, const int* __restrict__ pi1,
    const float* __restrict__ pv2,
    const float* __restrict__ sumsq, const float* __restrict__ xlo_n,
    const float* __restrict__ xr_n, const unsigned* __restrict__ maxes,
    float* __restrict__ out_idx, int* __restrict__ idxbuf,
    float* __restrict__ counts, int* __restrict__ rcnt, int* __restrict__ rlist)
{
  int r = blockIdx.x * 256 + threadIdx.x;
  float m1 = pv1[r]; int i1 = pi1[r]; float m2 = pv2[r];
#pragma unroll
  for (int gg = 1; gg < 8; ++gg) {
    float o1 = pv1[gg * N_ROWS + r];
    int oi = pi1[gg * N_ROWS + r];
    float o2 = pv2[gg * N_ROWS + r];
    float big = fmaxf(m1, o1);
    bool cnd = o1 < m1;
    m1 = fminf(m1, o1);
    i1 = cnd ? oi : i1;
    m2 = fminf(fminf(m2, o2), big);
  }
  float maxL = __uint_as_float(maxes[0]);   // max ||c_lo||
  float maxC = __uint_as_float(maxes[1]);   // max ||c||
  float maxR = __uint_as_float(maxes[2]);   // max ||r_c||
  float xn = sqrtf(sumsq[r]);
  // omitted = x_lo.c_lo + r_x.c + (x - r_x).r_c  -> certified bound + fp32 slack
  float W = 2.0f * (xlo_n[r] * maxL + xr_n[r] * maxC + (xn + xr_n[r]) * maxR) + 4e-4f;
  out_idx[r] = (float)i1;
  idxbuf[r] = i1;
  if (m2 - m1 >= W) {
    atomicAdd(&counts[i1], 1.0f);
  } else {
    int p = atomicAdd(rcnt, 1);
    rlist[p] = r;
  }
}

// exact fp32 re-solve: one row per block (grid-stride), wave-per-centroid,
// coalesced float4 loads (64 lanes span one centroid row)
__global__ __launch_bounds__(256) void vq_rescue(
    const float* __restrict__ X, const float* __restrict__ C,
    const float* __restrict__ sumsq, const float* __restrict__ csq,
    const int* __restrict__ rcnt, const int* __restrict__ rlist,
    float* __restrict__ out_idx, int* __restrict__ idxbuf, float* __restrict__ counts)
{
  __shared__ float swv[4];
  __shared__ int swi[4];
  const int nr = *rcnt;
  const int wave = threadIdx.x >> 6, lane = threadIdx.x & 63;
  for (int e = blockIdx.x; e < nr; e += 512) {
    const int r = rlist[e];
    const float4 x4 = *(const float4*)(X + (size_t)r * DIM + lane * 4);
    const float sx = sumsq[r];
    float bv = 3.4e38f;
    int bi = 0;
    for (int c = wave * 512; c < wave * 512 + 512; ++c) {
      float4 c4 = *(const float4*)(C + (size_t)c * DIM + lane * 4);
      float p = x4.x * c4.x + x4.y * c4.y + x4.z * c4.z + x4.w * c4.w;
#pragma unroll
      for (int off = 1; off < 64; off <<= 1) p += __shfl_xor(p, off);
      float d = (sx - 2.0f * p) + csq[c];
      if (d < bv) { bv = d; bi = c; }   // ascending c: strict < gives lowest-idx tie
    }
    if (lane == 0) { swv[wave] = bv; swi[wave] = bi; }
    __syncthreads();
    if (threadIdx.x == 0) {
      float fv = swv[0]; int fi = swi[0];
#pragma unroll
      for (int w = 1; w < 4; ++w) {
        if (swv[w] < fv || (swv[w] == fv && swi[w] < fi)) { fv = swv[w]; fi = swi[w]; }
      }
      out_idx[r] = (float)fi;
      idxbuf[r] = fi;
      atomicAdd(&counts[fi], 1.0f);
    }
    __syncthreads();
  }
}

// ============================================================================
//                     fp32 FALLBACK PATH (round-1 kernels)
// ============================================================================

__global__ __launch_bounds__(256) void vq_precompute(
    const float* __restrict__ X, const float* __restrict__ C,
    float* __restrict__ sumsq, float* __restrict__ csq, float* __restrict__ counts)
{
  int bid = blockIdx.x, tid = threadIdx.x;
  int wave = tid >> 6, lane = tid & 63;
  if (bid < 8192) {
    int row = bid * 4 + wave;
    float4 v = *(const float4*)(X + (size_t)row * DIM + lane * 4);
    float s = v.x * v.x + v.y * v.y + v.z * v.z + v.w * v.w;
#pragma unroll
    for (int off = 32; off > 0; off >>= 1) s += __shfl_down(s, off);
    if (lane == 0) sumsq[row] = s;
  } else if (bid < 8704) {
    int cent = (bid - 8192) * 4 + wave;
    float4 v = *(const float4*)(C + (size_t)cent * DIM + lane * 4);
    float s = v.x * v.x + v.y * v.y + v.z * v.z + v.w * v.w;
#pragma unroll
    for (int off = 32; off > 0; off >>= 1) s += __shfl_down(s, off);
    if (lane == 0) csq[cent] = s;
  } else {
    for (int i = tid; i < KCENT; i += 256) counts[i] = 0.0f;
  }
}

__global__ __launch_bounds__(256) void vq_argmin(
    const float* __restrict__ X, const float* __restrict__ C,
    const float* __restrict__ sumsq, const float* __restrict__ csq,
    float* __restrict__ pval, int* __restrict__ pidx)
{
  __shared__ __align__(16) float sA[BM * LSTR];
  __shared__ __align__(16) float sB[BN * LSTR];

  const int tid = threadIdx.x;
  const int tx = tid & 15, ty = tid >> 4;
  const int row0 = blockIdx.x * BM;
  const int g = blockIdx.y;
  const int cg0 = g * CPG;

  float sx[4];
#pragma unroll
  for (int m = 0; m < 4; ++m) sx[m] = sumsq[row0 + ty + 16 * m];

  float rmin[4];
  int ridx[4];
#pragma unroll
  for (int m = 0; m < 4; ++m) { rmin[m] = 3.4e38f; ridx[m] = 0; }

  for (int t = 0; t < CPG / BN; ++t) {
    const int c0 = cg0 + t * BN;
    float acc[4][4];
#pragma unroll
    for (int m = 0; m < 4; ++m)
#pragma unroll
      for (int n = 0; n < 4; ++n) acc[m][n] = 0.0f;

    for (int kc = 0; kc < DIM; kc += BKK) {
      __syncthreads();
#pragma unroll
      for (int s = 0; s < 2; ++s) {
        int id = tid + s * 256;
        int rr = id >> 3;
        int c4 = (id & 7) << 2;
        float4 va = *(const float4*)(X + (size_t)(row0 + rr) * DIM + kc + c4);
        *(float4*)&sA[rr * LSTR + c4] = va;
        float4 vb = *(const float4*)(C + (size_t)(c0 + rr) * DIM + kc + c4);
        *(float4*)&sB[rr * LSTR + c4] = vb;
      }
      __syncthreads();
#pragma unroll
      for (int j = 0; j < BKK; j += 4) {
        float4 a[4], b[4];
#pragma unroll
        for (int m = 0; m < 4; ++m) a[m] = *(const float4*)&sA[(ty + 16 * m) * LSTR + j];
#pragma unroll
        for (int n = 0; n < 4; ++n) b[n] = *(const float4*)&sB[(tx + 16 * n) * LSTR + j];
#pragma unroll
        for (int m = 0; m < 4; ++m)
#pragma unroll
          for (int n = 0; n < 4; ++n)
            acc[m][n] += a[m].x * b[n].x + a[m].y * b[n].y + a[m].z * b[n].z + a[m].w * b[n].w;
      }
    }

#pragma unroll
    for (int m = 0; m < 4; ++m) {
#pragma unroll
      for (int n = 0; n < 4; ++n) {
        int cent = c0 + tx + 16 * n;
        float d = (sx[m] - 2.0f * acc[m][n]) + csq[cent];
        if (d < rmin[m]) { rmin[m] = d; ridx[m] = cent; }
      }
    }
  }

  __syncthreads();
  float* rv = sA;
  int* ri = (int*)sB;
#pragma unroll
  for (int m = 0; m < 4; ++m) {
    rv[(ty + 16 * m) * 16 + tx] = rmin[m];
    ri[(ty + 16 * m) * 16 + tx] = ridx[m];
  }
  __syncthreads();
  if (tid < 64) {
    float bvv = rv[tid * 16];
    int bii = ri[tid * 16];
#pragma unroll
    for (int t2 = 1; t2 < 16; ++t2) {
      float v = rv[tid * 16 + t2];
      int i = ri[tid * 16 + t2];
      if (v < bvv || (v == bvv && i < bii)) { bvv = v; bii = i; }
    }
    pval[g * N_ROWS + row0 + tid] = bvv;
    pidx[g * N_ROWS + row0 + tid] = bii;
  }
}

__global__ __launch_bounds__(256) void vq_reduce(
    const float* __restrict__ pval, const int* __restrict__ pidx,
    float* __restrict__ out_idx, int* __restrict__ idxbuf, float* __restrict__ counts)
{
  int r = blockIdx.x * 256 + threadIdx.x;
  float bv = pval[r];
  int bi = pidx[r];
#pragma unroll
  for (int gg = 1; gg < NSPLIT; ++gg) {
    float v = pval[gg * N_ROWS + r];
    int i = pidx[gg * N_ROWS + r];
    if (v < bv || (v == bv && i < bi)) { bv = v; bi = i; }
  }
  out_idx[r] = (float)bi;
  idxbuf[r] = bi;
  atomicAdd(&counts[bi], 1.0f);
}

// ---------------- shared outputs kernel -------------------------------------
__global__ __launch_bounds__(256) void vq_outputs(
    const float* __restrict__ X, const float* __restrict__ C,
    const float* __restrict__ cc, const int* __restrict__ idxbuf,
    const float* __restrict__ counts, float* __restrict__ out)
{
  int bid = blockIdx.x, tid = threadIdx.x;
  if (bid < 8192) {
    int f4 = bid * 256 + tid;
    int row = f4 >> 6;
    int col = (f4 & 63) << 2;
    int idx = idxbuf[row];
    float4 x = *(const float4*)(X + (size_t)row * DIM + col);
    float4 q = *(const float4*)(C + (size_t)idx * DIM + col);
    float4 o, l;
    float dx = q.x - x.x, dy = q.y - x.y, dz = q.z - x.z, dw = q.w - x.w;
    o.x = x.x + dx; o.y = x.y + dy; o.z = x.z + dz; o.w = x.w + dw;
    float s0 = dx * dx, s1 = dy * dy, s2 = dz * dz, s3 = dw * dw;
    l.x = s0 + 0.25f * s0; l.y = s1 + 0.25f * s1;
    l.z = s2 + 0.25f * s2; l.w = s3 + 0.25f * s3;
    *(float4*)(out + OUT_Q + (size_t)f4 * 4) = o;
    *(float4*)(out + OUT_LOSS + (size_t)f4 * 4) = l;
  } else if (bid < 8704) {
    int f4 = (bid - 8192) * 256 + tid;
    float4 v = *(const float4*)(C + (size_t)f4 * 4);
    *(float4*)(out + OUT_CB + (size_t)f4 * 4) = v;
  } else {
    for (int i = tid; i < KCENT; i += 256)
      out[OUT_CNT + i] = 0.99f * cc[i] + 0.01f * counts[i];
  }
}

// ============================================================================
extern "C" void kernel_launch(void* const* d_in, const int* in_sizes, int n_in,
                              void* d_out, int out_size, void* d_ws, size_t ws_size,
                              hipStream_t stream) {
  const float* X = (const float*)d_in[0];
  const float* C = (const float*)d_in[1];
  const float* cc = (const float*)d_in[2];
  float* out = (float*)d_out;
  char* wsb = (char*)d_ws;

  if (ws_size >= WS_NEED) {
    // ---------------- MFMA path ----------------
    _Float16* A2 = (_Float16*)(wsb + WB_A2);
    _Float16* B2 = (_Float16*)(wsb + WB_B2);
    float* pv1 = (float*)(wsb + WB_PV1);
    int* pi1 = (int*)(wsb + WB_PI1);
    float* pv2 = (float*)(wsb + WB_PV2);
    float* sumsq = (float*)(wsb + WB_SUMSQ);
    float* xlo_n = (float*)(wsb + WB_XLO);
    float* xr_n = (float*)(wsb + WB_XR);
    float* csq = (float*)(wsb + WB_CSQ);
    float* counts = (float*)(wsb + WB_COUNTS);
    int* idxbuf = (int*)(wsb + WB_IDXBUF);
    int* rlist = (int*)(wsb + WB_RLIST);
    int* rcnt = (int*)(wsb + WB_MISC);
    unsigned* maxes = (unsigned*)(wsb + WB_MISC + 8);

    vq_init<<<1, 256, 0, stream>>>(counts, rcnt, maxes);
    vq_conv_x<<<N_ROWS / 4, 256, 0, stream>>>(X, A2, sumsq, xlo_n, xr_n);
    vq_conv_c<<<KCENT / 4, 256, 0, stream>>>(C, B2, csq, maxes);
    vq_mfma<<<dim3(4, N_ROWS / GBM), 256, 0, stream>>>(A2, B2, csq, pv1, pi1, pv2);
    vq_flagreduce<<<N_ROWS / 256, 256, 0, stream>>>(
        pv1, pi1, pv2, sumsq, xlo_n, xr_n, maxes,
        out + OUT_IDX, idxbuf, counts, rcnt, rlist);
    vq_rescue<<<512, 256, 0, stream>>>(X, C, sumsq, csq, rcnt, rlist,
                                       out + OUT_IDX, idxbuf, counts);
    vq_outputs<<<8705, 256, 0, stream>>>(X, C, cc, idxbuf, counts, out);
  } else {
    // ---------------- fp32 fallback (round-1) ----------------
    float* ws = (float*)d_ws;
    float* sumsq = ws + WS_SUMSQ;
    float* csq = ws + WS_CSQ;
    float* counts = ws + WS_COUNTS;
    int* idxbuf = (int*)(ws + WS_IDX);
    float* pval = ws + WS_PVAL;
    int* pidx = (int*)(ws + WS_PIDX);

    vq_precompute<<<8705, 256, 0, stream>>>(X, C, sumsq, csq, counts);
    vq_argmin<<<dim3(N_ROWS / BM, NSPLIT), 256, 0, stream>>>(X, C, sumsq, csq, pval, pidx);
    vq_reduce<<<N_ROWS / 256, 256, 0, stream>>>(pval, pidx, out + OUT_IDX, idxbuf, counts);
    vq_outputs<<<8705, 256, 0, stream>>>(X, C, cc, idxbuf, counts, out);
  }
}

// Round 5
// 447.772 us; speedup vs baseline: 1.1031x; 1.1031x over previous
//
#include <hip/hip_runtime.h>
#include <math.h>

typedef unsigned short ushort_t;

#define N_ROWS 32768
#define DIM 256
#define KCENT 2048

// ---------------- fp32 fallback path constants (round-1 kernel) -------------
#define NSPLIT 4
#define CPG (KCENT / NSPLIT)
#define BM 64
#define BN 64
#define BKK 32
#define LSTR 36

#define WS_SUMSQ  0
#define WS_CSQ    32768
#define WS_COUNTS 34816
#define WS_IDX    36864
#define WS_PVAL   69632
#define WS_PIDX   200704

// ---------------- output layout (float offsets) -----------------------------
#define OUT_Q    0
#define OUT_LOSS 8388608
#define OUT_IDX  16777216
#define OUT_CB   16809984
#define OUT_CNT  17334272

// ---------------- MFMA path workspace (byte offsets) ------------------------
// 8 partial groups per row (4 block-groups x 2 wn-halves)
#define WB_A2     0UL            // 32768 x 512 f16 = [x_hi | x_lo]  (32 MB)
#define WB_B2     33554432UL     // 2048 x 512 f16 = [c_hi | c_lo]   (2 MB)
#define WB_PV1    35651584UL     // 8 x 32768 f32  (1 MB)
#define WB_PI1    36700160UL     // 8 x 32768 i32  (1 MB)
#define WB_PV2    37748736UL     // 8 x 32768 f32  (1 MB)
#define WB_SUMSQ  38797312UL     // 32768 f32 (exact ||x||^2)
#define WB_XLO    38928384UL     // 32768 f32 (||x_lo||)
#define WB_XR     39059456UL     // 32768 f32 (||r_x||)
#define WB_CSQ    39190528UL     // 2048 f32 (exact ||c||^2)
#define WB_COUNTS 39198720UL     // 2048 f32
#define WB_IDXBUF 39206912UL     // 32768 i32
#define WB_RLIST  39337984UL     // 32768 i32
#define WB_MISC   39469056UL     // rcnt(i32) @ +0, maxes(u32[3]) @ +8
#define WS_NEED   39469120UL

// ---------------- types & helpers -------------------------------------------
typedef _Float16 half4 __attribute__((ext_vector_type(4)));
typedef _Float16 half8 __attribute__((ext_vector_type(8)));
typedef float f32x4 __attribute__((ext_vector_type(4)));

#define ASYNC_COPY16(gptr, lptr)                                               \
  __builtin_amdgcn_global_load_lds(                                            \
      (const __attribute__((address_space(1))) void*)(gptr),                   \
      (__attribute__((address_space(3))) void*)(lptr), 16, 0, 0)

// ============================================================================
//                               MFMA PATH (fp16 3-term split)
// ============================================================================

__global__ __launch_bounds__(256) void vq_init(float* counts, int* rcnt, unsigned* maxes) {
  int tid = threadIdx.x;
  for (int i = tid; i < KCENT; i += 256) counts[i] = 0.0f;
  if (tid == 0) { *rcnt = 0; maxes[0] = 0u; maxes[1] = 0u; maxes[2] = 0u; }
}

// split X into f16 hi/lo + per-row norms; one wave per row
__global__ __launch_bounds__(256) void vq_conv_x(
    const float* __restrict__ X, _Float16* __restrict__ A2,
    float* __restrict__ sumsq, float* __restrict__ xlo_n, float* __restrict__ xr_n)
{
  int row = blockIdx.x * 4 + (threadIdx.x >> 6);
  int lane = threadIdx.x & 63;
  float4 v = *(const float4*)(X + (size_t)row * DIM + lane * 4);
  float xv[4] = {v.x, v.y, v.z, v.w};
  half4 hv, lv;
  float s2 = 0.f, l2 = 0.f, r2 = 0.f;
#pragma unroll
  for (int e = 0; e < 4; ++e) {
    float x = xv[e];
    _Float16 h = (_Float16)x;          // RNE
    float hf = (float)h;
    float lrem = x - hf;
    _Float16 l = (_Float16)lrem;
    float lf = (float)l;
    float r = lrem - lf;
    hv[e] = h; lv[e] = l;
    s2 += x * x; l2 += lf * lf; r2 += r * r;
  }
  *(half4*)(A2 + (size_t)row * 512 + lane * 4) = hv;
  *(half4*)(A2 + (size_t)row * 512 + 256 + lane * 4) = lv;
#pragma unroll
  for (int off = 32; off > 0; off >>= 1) {
    s2 += __shfl_down(s2, off);
    l2 += __shfl_down(l2, off);
    r2 += __shfl_down(r2, off);
  }
  if (lane == 0) { sumsq[row] = s2; xlo_n[row] = sqrtf(l2); xr_n[row] = sqrtf(r2); }
}

// split C into f16 [hi|lo] + per-cent norms + global maxes; one wave per centroid
__global__ __launch_bounds__(256) void vq_conv_c(
    const float* __restrict__ C, _Float16* __restrict__ B2,
    float* __restrict__ csq, unsigned* __restrict__ maxes)
{
  int c = blockIdx.x * 4 + (threadIdx.x >> 6);
  int lane = threadIdx.x & 63;
  float4 v = *(const float4*)(C + (size_t)c * DIM + lane * 4);
  float xv[4] = {v.x, v.y, v.z, v.w};
  half4 hv, lv;
  float s2 = 0.f, l2 = 0.f, r2 = 0.f;
#pragma unroll
  for (int e = 0; e < 4; ++e) {
    float x = xv[e];
    _Float16 h = (_Float16)x;
    float hf = (float)h;
    float lrem = x - hf;
    _Float16 l = (_Float16)lrem;
    float lf = (float)l;
    float r = lrem - lf;
    hv[e] = h; lv[e] = l;
    s2 += x * x; l2 += lf * lf; r2 += r * r;
  }
  *(half4*)(B2 + (size_t)c * 512 + lane * 4) = hv;
  *(half4*)(B2 + (size_t)c * 512 + 256 + lane * 4) = lv;
#pragma unroll
  for (int off = 32; off > 0; off >>= 1) {
    s2 += __shfl_down(s2, off);
    l2 += __shfl_down(l2, off);
    r2 += __shfl_down(r2, off);
  }
  if (lane == 0) {
    csq[c] = s2;
    atomicMax(&maxes[0], __float_as_uint(sqrtf(l2)));   // max ||c_lo||
    atomicMax(&maxes[1], __float_as_uint(sqrtf(s2)));   // max ||c||
    atomicMax(&maxes[2], __float_as_uint(sqrtf(r2)));   // max ||r_c||
  }
}

// MFMA GEMM (virtual K=768: hi*hi + lo*hi + hi*lo) + fused argmin(+2nd-min).
// Block: 128 rows x 512 cents (4 internal 128-col tiles), grid (4, 256).
// Partial-group slot = g*2 + wn (wn halves cover different cents of same rows).
#define GBM 128
#define GBN 128
#define GBK 32
__global__ __launch_bounds__(256) void vq_mfma(
    const _Float16* __restrict__ A2, const _Float16* __restrict__ B2,
    const float* __restrict__ csq,
    float* __restrict__ pv1, int* __restrict__ pi1, float* __restrict__ pv2)
{
  __shared__ __align__(16) _Float16 sA[GBM * GBK];
  __shared__ __align__(16) _Float16 sB[GBN * GBK];

  const int tid = threadIdx.x;
  const int wave = tid >> 6, lane = tid & 63;
  const int lc = lane & 15, quad = lane >> 4;
  const int wm = wave >> 1, wn = wave & 1;
  const int row0 = blockIdx.y * GBM;
  const int g = blockIdx.x;           // cent group: cents [g*512, g*512+512)

  float m1[4][4], m2[4][4];
  int i1v[4][4];
#pragma unroll
  for (int i = 0; i < 4; ++i)
#pragma unroll
    for (int r = 0; r < 4; ++r) { m1[i][r] = 3.4e38f; m2[i][r] = 3.4e38f; i1v[i][r] = 0; }

  const int st_row = wave * 32 + (lane >> 2);
  const int st_ko = (lane & 3) * 8;
  const _Float16* gA = A2 + (size_t)(row0 + st_row) * 512 + st_ko;

  for (int ct = 0; ct < 4; ++ct) {
    const int cb0 = g * 512 + ct * 128;
    const _Float16* gB = B2 + (size_t)(cb0 + st_row) * 512 + st_ko;
    float cs[4];
#pragma unroll
    for (int j = 0; j < 4; ++j) cs[j] = csq[cb0 + wn * 64 + j * 16 + lc];

    f32x4 acc[4][4] = {};

    for (int kt = 0; kt < 24; ++kt) {
      const int a_k0 = (kt < 16 ? kt : kt - 16) * 32;   // A: [hi | lo | hi]
      const int b_k0 = (kt < 8 ? kt : kt - 8) * 32;     // B: [hi | hi | lo]
      __syncthreads();
#pragma unroll
      for (int j = 0; j < 2; ++j) {
        ASYNC_COPY16(gA + (size_t)(j * 16) * 512 + a_k0, &sA[(wave * 32 + j * 16) * GBK]);
        ASYNC_COPY16(gB + (size_t)(j * 16) * 512 + b_k0, &sB[(wave * 32 + j * 16) * GBK]);
      }
      __syncthreads();
      half8 fa[4], fb[4];
#pragma unroll
      for (int i = 0; i < 4; ++i)
        fa[i] = *(const half8*)&sA[(wm * 64 + i * 16 + lc) * GBK + quad * 8];
#pragma unroll
      for (int j = 0; j < 4; ++j)
        fb[j] = *(const half8*)&sB[(wn * 64 + j * 16 + lc) * GBK + quad * 8];
#pragma unroll
      for (int i = 0; i < 4; ++i)
#pragma unroll
        for (int j = 0; j < 4; ++j)
          acc[i][j] = __builtin_amdgcn_mfma_f32_16x16x32_f16(fa[i], fb[j], acc[i][j], 0, 0, 0);
    }

#pragma unroll
    for (int i = 0; i < 4; ++i) {
#pragma unroll
      for (int j = 0; j < 4; ++j) {
        const int cent = cb0 + wn * 64 + j * 16 + lc;
#pragma unroll
        for (int r = 0; r < 4; ++r) {
          float d = fmaf(-2.0f, acc[i][j][r], cs[j]);
          bool cnd = d < m1[i][r];
          i1v[i][r] = cnd ? cent : i1v[i][r];
          m2[i][r] = fminf(m2[i][r], fmaxf(d, m1[i][r]));
          m1[i][r] = fminf(d, m1[i][r]);
        }
      }
    }
  }

#pragma unroll
  for (int i = 0; i < 4; ++i) {
#pragma unroll
    for (int r = 0; r < 4; ++r) {
      float a1 = m1[i][r], a2 = m2[i][r];
      int ai = i1v[i][r];
#pragma unroll
      for (int off = 1; off < 16; off <<= 1) {
        float o1 = __shfl_xor(a1, off);
        int oi = __shfl_xor(ai, off);
        float o2 = __shfl_xor(a2, off);
        float big = fmaxf(a1, o1);
        bool cnd = o1 < a1;
        a1 = fminf(a1, o1);
        ai = cnd ? oi : ai;
        a2 = fminf(fminf(a2, o2), big);
      }
      if (lc == 0) {
        const int row = row0 + wm * 64 + i * 16 + quad * 4 + r;
        const int slot = g * 2 + wn;
        pv1[slot * N_ROWS + row] = a1;
        pi1[slot * N_ROWS + row] = ai;
        pv2[slot * N_ROWS + row] = a2;
      }
    }
  }
}

// merge 8 partial groups/row; certify via window; flag uncertified rows
__global__ __launch_bounds__(256) void vq_flagreduce(
    const float* __restrict__ pv1, const int* __restrict__ pi1,
    const float* __restrict__ pv2,
    const float* __restrict__ sumsq, const float* __restrict__ xlo_n,
    const float* __restrict__ xr_n, const unsigned* __restrict__ maxes,
    float* __restrict__ out_idx, int* __restrict__ idxbuf,
    float* __restrict__ counts, int* __restrict__ rcnt, int* __restrict__ rlist)
{
  int r = blockIdx.x * 256 + threadIdx.x;
  float m1 = pv1[r]; int i1 = pi1[r]; float m2 = pv2[r];
#pragma unroll
  for (int gg = 1; gg < 8; ++gg) {
    float o1 = pv1[gg * N_ROWS + r];
    int oi = pi1[gg * N_ROWS + r];
    float o2 = pv2[gg * N_ROWS + r];
    float big = fmaxf(m1, o1);
    bool cnd = o1 < m1;
    m1 = fminf(m1, o1);
    i1 = cnd ? oi : i1;
    m2 = fminf(fminf(m2, o2), big);
  }
  float maxL = __uint_as_float(maxes[0]);   // max ||c_lo||
  float maxC = __uint_as_float(maxes[1]);   // max ||c||
  float maxR = __uint_as_float(maxes[2]);   // max ||r_c||
  float xn = sqrtf(sumsq[r]);
  // omitted = x_lo.c_lo + r_x.c + (x - r_x).r_c  -> certified bound + fp32 slack
  float W = 2.0f * (xlo_n[r] * maxL + xr_n[r] * maxC + (xn + xr_n[r]) * maxR) + 4e-4f;
  out_idx[r] = (float)i1;
  idxbuf[r] = i1;
  if (m2 - m1 >= W) {
    atomicAdd(&counts[i1], 1.0f);
  } else {
    int p = atomicAdd(rcnt, 1);
    rlist[p] = r;
  }
}

// exact fp32 re-solve, intra-row parallel: block = 4 flagged rows; thread t
// owns cents [t*8, t*8+8); x broadcast from LDS; one shfl reduce per row.
#define RROWS 4
__global__ __launch_bounds__(256) void vq_rescue(
    const float* __restrict__ X, const float* __restrict__ C,
    const float* __restrict__ sumsq, const float* __restrict__ csq,
    const int* __restrict__ rcnt, const int* __restrict__ rlist,
    float* __restrict__ out_idx, int* __restrict__ idxbuf, float* __restrict__ counts)
{
  __shared__ __align__(16) float sx[RROWS * DIM];
  __shared__ float ssq[RROWS];
  __shared__ int srow[RROWS];
  __shared__ float swv[4][RROWS];
  __shared__ int swi[4][RROWS];
  const int nr = *rcnt;
  const int tid = threadIdx.x;
  const int wave = tid >> 6, lane = tid & 63;
  const int c0 = tid * 8;

  for (int base = blockIdx.x * RROWS; base < nr; base += 1024 * RROWS) {
    const int nrow = min(RROWS, nr - base);
    __syncthreads();                       // protect prior-iter LDS reads
#pragma unroll
    for (int e = 0; e < RROWS; ++e) {
      if (e < nrow) {
        int r = rlist[base + e];
        sx[e * DIM + tid] = X[(size_t)r * DIM + tid];
      }
    }
    if (tid < nrow) {
      int r = rlist[base + tid];
      srow[tid] = r;
      ssq[tid] = sumsq[r];
    }
    __syncthreads();

    float acc[RROWS][8];
#pragma unroll
    for (int e = 0; e < RROWS; ++e)
#pragma unroll
      for (int j = 0; j < 8; ++j) acc[e][j] = 0.0f;

    for (int k = 0; k < DIM; k += 4) {
      float4 xr[RROWS];
#pragma unroll
      for (int e = 0; e < RROWS; ++e) xr[e] = *(const float4*)&sx[e * DIM + k];
#pragma unroll
      for (int j = 0; j < 8; ++j) {
        float4 c4 = *(const float4*)(C + (size_t)(c0 + j) * DIM + k);
#pragma unroll
        for (int e = 0; e < RROWS; ++e)
          acc[e][j] += xr[e].x * c4.x + xr[e].y * c4.y + xr[e].z * c4.z + xr[e].w * c4.w;
      }
    }

#pragma unroll
    for (int e = 0; e < RROWS; ++e) {
      float sxq = ssq[e];
      float bv = 3.4e38f;
      int bi = 0;
#pragma unroll
      for (int j = 0; j < 8; ++j) {
        int c = c0 + j;
        float d = (sxq - 2.0f * acc[e][j]) + csq[c];  // exact ref fp32 op order
        if (d < bv) { bv = d; bi = c; }               // ascending c: lowest-idx tie
      }
#pragma unroll
      for (int off = 1; off < 64; off <<= 1) {
        float ov = __shfl_xor(bv, off);
        int oi = __shfl_xor(bi, off);
        bool take = (ov < bv) || (ov == bv && oi < bi);
        bv = take ? ov : bv;
        bi = take ? oi : bi;
      }
      if (lane == 0) { swv[wave][e] = bv; swi[wave][e] = bi; }
    }
    __syncthreads();
    if (tid < nrow) {
      float fv = swv[0][tid]; int fi = swi[0][tid];
#pragma unroll
      for (int w = 1; w < 4; ++w) {
        float ov = swv[w][tid]; int oi = swi[w][tid];
        if (ov < fv || (ov == fv && oi < fi)) { fv = ov; fi = oi; }
      }
      int r = srow[tid];
      out_idx[r] = (float)fi;
      idxbuf[r] = fi;
      atomicAdd(&counts[fi], 1.0f);
    }
  }
}

// ============================================================================
//                     fp32 FALLBACK PATH (round-1 kernels)
// ============================================================================

__global__ __launch_bounds__(256) void vq_precompute(
    const float* __restrict__ X, const float* __restrict__ C,
    float* __restrict__ sumsq, float* __restrict__ csq, float* __restrict__ counts)
{
  int bid = blockIdx.x, tid = threadIdx.x;
  int wave = tid >> 6, lane = tid & 63;
  if (bid < 8192) {
    int row = bid * 4 + wave;
    float4 v = *(const float4*)(X + (size_t)row * DIM + lane * 4);
    float s = v.x * v.x + v.y * v.y + v.z * v.z + v.w * v.w;
#pragma unroll
    for (int off = 32; off > 0; off >>= 1) s += __shfl_down(s, off);
    if (lane == 0) sumsq[row] = s;
  } else if (bid < 8704) {
    int cent = (bid - 8192) * 4 + wave;
    float4 v = *(const float4*)(C + (size_t)cent * DIM + lane * 4);
    float s = v.x * v.x + v.y * v.y + v.z * v.z + v.w * v.w;
#pragma unroll
    for (int off = 32; off > 0; off >>= 1) s += __shfl_down(s, off);
    if (lane == 0) csq[cent] = s;
  } else {
    for (int i = tid; i < KCENT; i += 256) counts[i] = 0.0f;
  }
}

__global__ __launch_bounds__(256) void vq_argmin(
    const float* __restrict__ X, const float* __restrict__ C,
    const float* __restrict__ sumsq, const float* __restrict__ csq,
    float* __restrict__ pval, int* __restrict__ pidx)
{
  __shared__ __align__(16) float sA[BM * LSTR];
  __shared__ __align__(16) float sB[BN * LSTR];

  const int tid = threadIdx.x;
  const int tx = tid & 15, ty = tid >> 4;
  const int row0 = blockIdx.x * BM;
  const int g = blockIdx.y;
  const int cg0 = g * CPG;

  float sx[4];
#pragma unroll
  for (int m = 0; m < 4; ++m) sx[m] = sumsq[row0 + ty + 16 * m];

  float rmin[4];
  int ridx[4];
#pragma unroll
  for (int m = 0; m < 4; ++m) { rmin[m] = 3.4e38f; ridx[m] = 0; }

  for (int t = 0; t < CPG / BN; ++t) {
    const int c0 = cg0 + t * BN;
    float acc[4][4];
#pragma unroll
    for (int m = 0; m < 4; ++m)
#pragma unroll
      for (int n = 0; n < 4; ++n) acc[m][n] = 0.0f;

    for (int kc = 0; kc < DIM; kc += BKK) {
      __syncthreads();
#pragma unroll
      for (int s = 0; s < 2; ++s) {
        int id = tid + s * 256;
        int rr = id >> 3;
        int c4 = (id & 7) << 2;
        float4 va = *(const float4*)(X + (size_t)(row0 + rr) * DIM + kc + c4);
        *(float4*)&sA[rr * LSTR + c4] = va;
        float4 vb = *(const float4*)(C + (size_t)(c0 + rr) * DIM + kc + c4);
        *(float4*)&sB[rr * LSTR + c4] = vb;
      }
      __syncthreads();
#pragma unroll
      for (int j = 0; j < BKK; j += 4) {
        float4 a[4], b[4];
#pragma unroll
        for (int m = 0; m < 4; ++m) a[m] = *(const float4*)&sA[(ty + 16 * m) * LSTR + j];
#pragma unroll
        for (int n = 0; n < 4; ++n) b[n] = *(const float4*)&sB[(tx + 16 * n) * LSTR + j];
#pragma unroll
        for (int m = 0; m < 4; ++m)
#pragma unroll
          for (int n = 0; n < 4; ++n)
            acc[m][n] += a[m].x * b[n].x + a[m].y * b[n].y + a[m].z * b[n].z + a[m].w * b[n].w;
      }
    }

#pragma unroll
    for (int m = 0; m < 4; ++m) {
#pragma unroll
      for (int n = 0; n < 4; ++n) {
        int cent = c0 + tx + 16 * n;
        float d = (sx[m] - 2.0f * acc[m][n]) + csq[cent];
        if (d < rmin[m]) { rmin[m] = d; ridx[m] = cent; }
      }
    }
  }

  __syncthreads();
  float* rv = sA;
  int* ri = (int*)sB;
#pragma unroll
  for (int m = 0; m < 4; ++m) {
    rv[(ty + 16 * m) * 16 + tx] = rmin[m];
    ri[(ty + 16 * m) * 16 + tx] = ridx[m];
  }
  __syncthreads();
  if (tid < 64) {
    float bvv = rv[tid * 16];
    int bii = ri[tid * 16];
#pragma unroll
    for (int t2 = 1; t2 < 16; ++t2) {
      float v = rv[tid * 16 + t2];
      int i = ri[tid * 16 + t2];
      if (v < bvv || (v == bvv && i < bii)) { bvv = v; bii = i; }
    }
    pval[g * N_ROWS + row0 + tid] = bvv;
    pidx[g * N_ROWS + row0 + tid] = bii;
  }
}

__global__ __launch_bounds__(256) void vq_reduce(
    const float* __restrict__ pval, const int* __restrict__ pidx,
    float* __restrict__ out_idx, int* __restrict__ idxbuf, float* __restrict__ counts)
{
  int r = blockIdx.x * 256 + threadIdx.x;
  float bv = pval[r];
  int bi = pidx[r];
#pragma unroll
  for (int gg = 1; gg < NSPLIT; ++gg) {
    float v = pval[gg * N_ROWS + r];
    int i = pidx[gg * N_ROWS + r];
    if (v < bv || (v == bv && i < bi)) { bv = v; bi = i; }
  }
  out_idx[r] = (float)bi;
  idxbuf[r] = bi;
  atomicAdd(&counts[bi], 1.0f);
}

// ---------------- shared outputs kernel -------------------------------------
__global__ __launch_bounds__(256) void vq_outputs(
    const float* __restrict__ X, const float* __restrict__ C,
    const float* __restrict__ cc, const int* __restrict__ idxbuf,
    const float* __restrict__ counts, float* __restrict__ out)
{
  int bid = blockIdx.x, tid = threadIdx.x;
  if (bid < 8192) {
    int f4 = bid * 256 + tid;
    int row = f4 >> 6;
    int col = (f4 & 63) << 2;
    int idx = idxbuf[row];
    float4 x = *(const float4*)(X + (size_t)row * DIM + col);
    float4 q = *(const float4*)(C + (size_t)idx * DIM + col);
    float4 o, l;
    float dx = q.x - x.x, dy = q.y - x.y, dz = q.z - x.z, dw = q.w - x.w;
    o.x = x.x + dx; o.y = x.y + dy; o.z = x.z + dz; o.w = x.w + dw;
    float s0 = dx * dx, s1 = dy * dy, s2 = dz * dz, s3 = dw * dw;
    l.x = s0 + 0.25f * s0; l.y = s1 + 0.25f * s1;
    l.z = s2 + 0.25f * s2; l.w = s3 + 0.25f * s3;
    *(float4*)(out + OUT_Q + (size_t)f4 * 4) = o;
    *(float4*)(out + OUT_LOSS + (size_t)f4 * 4) = l;
  } else if (bid < 8704) {
    int f4 = (bid - 8192) * 256 + tid;
    float4 v = *(const float4*)(C + (size_t)f4 * 4);
    *(float4*)(out + OUT_CB + (size_t)f4 * 4) = v;
  } else {
    for (int i = tid; i < KCENT; i += 256)
      out[OUT_CNT + i] = 0.99f * cc[i] + 0.01f * counts[i];
  }
}

// ============================================================================
extern "C" void kernel_launch(void* const* d_in, const int* in_sizes, int n_in,
                              void* d_out, int out_size, void* d_ws, size_t ws_size,
                              hipStream_t stream) {
  const float* X = (const float*)d_in[0];
  const float* C = (const float*)d_in[1];
  const float* cc = (const float*)d_in[2];
  float* out = (float*)d_out;
  char* wsb = (char*)d_ws;

  if (ws_size >= WS_NEED) {
    // ---------------- MFMA path ----------------
    _Float16* A2 = (_Float16*)(wsb + WB_A2);
    _Float16* B2 = (_Float16*)(wsb + WB_B2);
    float* pv1 = (float*)(wsb + WB_PV1);
    int* pi1 = (int*)(wsb + WB_PI1);
    float* pv2 = (float*)(wsb + WB_PV2);
    float* sumsq = (float*)(wsb + WB_SUMSQ);
    float* xlo_n = (float*)(wsb + WB_XLO);
    float* xr_n = (float*)(wsb + WB_XR);
    float* csq = (float*)(wsb + WB_CSQ);
    float* counts = (float*)(wsb + WB_COUNTS);
    int* idxbuf = (int*)(wsb + WB_IDXBUF);
    int* rlist = (int*)(wsb + WB_RLIST);
    int* rcnt = (int*)(wsb + WB_MISC);
    unsigned* maxes = (unsigned*)(wsb + WB_MISC + 8);

    vq_init<<<1, 256, 0, stream>>>(counts, rcnt, maxes);
    vq_conv_x<<<N_ROWS / 4, 256, 0, stream>>>(X, A2, sumsq, xlo_n, xr_n);
    vq_conv_c<<<KCENT / 4, 256, 0, stream>>>(C, B2, csq, maxes);
    vq_mfma<<<dim3(4, N_ROWS / GBM), 256, 0, stream>>>(A2, B2, csq, pv1, pi1, pv2);
    vq_flagreduce<<<N_ROWS / 256, 256, 0, stream>>>(
        pv1, pi1, pv2, sumsq, xlo_n, xr_n, maxes,
        out + OUT_IDX, idxbuf, counts, rcnt, rlist);
    vq_rescue<<<1024, 256, 0, stream>>>(X, C, sumsq, csq, rcnt, rlist,
                                        out + OUT_IDX, idxbuf, counts);
    vq_outputs<<<8705, 256, 0, stream>>>(X, C, cc, idxbuf, counts, out);
  } else {
    // ---------------- fp32 fallback (round-1) ----------------
    float* ws = (float*)d_ws;
    float* sumsq = ws + WS_SUMSQ;
    float* csq = ws + WS_CSQ;
    float* counts = ws + WS_COUNTS;
    int* idxbuf = (int*)(ws + WS_IDX);
    float* pval = ws + WS_PVAL;
    int* pidx = (int*)(ws + WS_PIDX);

    vq_precompute<<<8705, 256, 0, stream>>>(X, C, sumsq, csq, counts);
    vq_argmin<<<dim3(N_ROWS / BM, NSPLIT), 256, 0, stream>>>(X, C, sumsq, csq, pval, pidx);
    vq_reduce<<<N_ROWS / 256, 256, 0, stream>>>(pval, pidx, out + OUT_IDX, idxbuf, counts);
    vq_outputs<<<8705, 256, 0, stream>>>(X, C, cc, idxbuf, counts, out);
  }
}